// Round 7
// baseline (337.292 us; speedup 1.0000x reference)
//
#include <hip/hip_runtime.h>
#include <math.h>

#define IN_C 128
#define OUT_C 64
#define ALPHA 0.2f

#define SCAN_BLOCK 256
#define SCAN_ITEMS 4
#define SCAN_TILE (SCAN_BLOCK * SCAN_ITEMS)  // 1024 elements per block

#define LDK 136  // padded halfwords per LDS row

#define SC_K 4    // edges per thread in hist/scatter
#define CURS 32   // cursor stride in ints: one counter per 128B line

typedef __attribute__((ext_vector_type(8))) short short8;
typedef __attribute__((ext_vector_type(4))) float v4f;

__device__ __forceinline__ ushort f2b(float f) {  // fp32 -> bf16 RNE
  unsigned u = __float_as_uint(f);
  u += 0x7fffu + ((u >> 16) & 1u);
  return (ushort)(u >> 16);
}
__device__ __forceinline__ float b2f(ushort h) {
  return __uint_as_float(((unsigned)h) << 16);
}

// ---------------------------------------------------------------------------
// Kernel 1: h = bf16(x) @ bf16(W) via MFMA 16x16x32, fp32 accumulate.
// ---------------------------------------------------------------------------
__global__ __launch_bounds__(256) void gemm_st_kernel(
    const float* __restrict__ x, const float* __restrict__ W,
    const float* __restrict__ a, ushort* __restrict__ hb,
    float* __restrict__ s, float* __restrict__ t, int n_nodes, int n_tiles) {
  __shared__ ushort xs[64 * LDK];
  __shared__ ushort ws[64 * LDK];

  const int tid = threadIdx.x;
  const int wave = tid >> 6;
  const int lane = tid & 63;
  const int li = lane & 15;
  const int quad = lane >> 4;

  for (int i = tid; i < IN_C * OUT_C; i += 256) {
    const int k = i >> 6;
    const int n = i & 63;
    ws[n * LDK + k] = f2b(W[i]);
  }
  __syncthreads();

  short8 bfrag[4][4];
#pragma unroll
  for (int ct = 0; ct < 4; ++ct)
#pragma unroll
    for (int kk = 0; kk < 4; ++kk)
      bfrag[ct][kk] =
          *(const short8*)&ws[(ct * 16 + li) * LDK + kk * 32 + quad * 8];

  float a1v[4], a2v[4];
#pragma unroll
  for (int ct = 0; ct < 4; ++ct) {
    a1v[ct] = a[ct * 16 + li];
    a2v[ct] = a[OUT_C + ct * 16 + li];
  }

  for (int tile = blockIdx.x; tile < n_tiles; tile += gridDim.x) {
    const int row0 = tile * 64;

    __syncthreads();
    for (int i = tid; i < 64 * (IN_C / 4); i += 256) {
      const int r = i >> 5;
      const int c4 = i & 31;
      int row = row0 + r;
      row = row < n_nodes ? row : n_nodes - 1;
      const float4 v = *(const float4*)&x[(size_t)row * IN_C + c4 * 4];
      uint2 p;
      p.x = (unsigned)f2b(v.x) | ((unsigned)f2b(v.y) << 16);
      p.y = (unsigned)f2b(v.z) | ((unsigned)f2b(v.w) << 16);
      *(uint2*)&xs[r * LDK + c4 * 4] = p;
    }
    __syncthreads();

    v4f acc[4];
#pragma unroll
    for (int ct = 0; ct < 4; ++ct) acc[ct] = (v4f){0.f, 0.f, 0.f, 0.f};

    const int rbase = wave * 16;
#pragma unroll
    for (int kk = 0; kk < 4; ++kk) {
      const short8 af =
          *(const short8*)&xs[(rbase + li) * LDK + kk * 32 + quad * 8];
#pragma unroll
      for (int ct = 0; ct < 4; ++ct)
        acc[ct] = __builtin_amdgcn_mfma_f32_16x16x32_bf16(af, bfrag[ct][kk],
                                                          acc[ct], 0, 0, 0);
    }

    const int growbase = row0 + rbase + quad * 4;
    float ps[4] = {0.f, 0.f, 0.f, 0.f};
    float pt[4] = {0.f, 0.f, 0.f, 0.f};
#pragma unroll
    for (int ct = 0; ct < 4; ++ct) {
#pragma unroll
      for (int r = 0; r < 4; ++r) {
        const float hv = acc[ct][r];
        ps[r] += hv * a1v[ct];
        pt[r] += hv * a2v[ct];
        const int grow = growbase + r;
        if (grow < n_nodes)
          hb[(size_t)grow * OUT_C + ct * 16 + li] = f2b(hv);
      }
    }
#pragma unroll
    for (int m = 1; m <= 8; m <<= 1) {
#pragma unroll
      for (int r = 0; r < 4; ++r) {
        ps[r] += __shfl_xor(ps[r], m, 64);
        pt[r] += __shfl_xor(pt[r], m, 64);
      }
    }
    if (li < 4) {
      const int grow = growbase + li;
      if (grow < n_nodes) {
        const float sv = li == 0 ? ps[0] : li == 1 ? ps[1] : li == 2 ? ps[2] : ps[3];
        const float tv = li == 0 ? pt[0] : li == 1 ? pt[1] : li == 2 ? pt[2] : pt[3];
        s[grow] = sv;
        t[grow] = tv;
      }
    }
  }
}

// ---------------------------------------------------------------------------
// CSR build: histogram -> 3-pass scan -> cursor scatter
// ---------------------------------------------------------------------------
__global__ __launch_bounds__(256) void hist_kernel(const int* __restrict__ src,
                                                   int* __restrict__ cnt,
                                                   int E) {
  const int base = blockIdx.x * (256 * SC_K) + threadIdx.x;
  int vs[SC_K];
  bool valid[SC_K];
#pragma unroll
  for (int i = 0; i < SC_K; ++i) {
    const int e = base + i * 256;
    valid[i] = (e < E);
    vs[i] = src[valid[i] ? e : 0];
  }
#pragma unroll
  for (int i = 0; i < SC_K; ++i)
    if (valid[i]) atomicAdd(&cnt[vs[i]], 1);
}

__global__ __launch_bounds__(SCAN_BLOCK) void scan_partial(
    const int* __restrict__ cnt, int* __restrict__ block_sums, int n) {
  const int tid = threadIdx.x;
  const int base = blockIdx.x * SCAN_TILE + tid * SCAN_ITEMS;
  int s = 0;
#pragma unroll
  for (int i = 0; i < SCAN_ITEMS; ++i) {
    const int idx = base + i;
    if (idx < n) s += cnt[idx];
  }
  __shared__ int wsum[SCAN_BLOCK / 64];
#pragma unroll
  for (int off = 32; off; off >>= 1) s += __shfl_down(s, off, 64);
  if ((tid & 63) == 0) wsum[tid >> 6] = s;
  __syncthreads();
  if (tid == 0) {
    int tot = 0;
#pragma unroll
    for (int w = 0; w < SCAN_BLOCK / 64; ++w) tot += wsum[w];
    block_sums[blockIdx.x] = tot;
  }
}

__global__ __launch_bounds__(1024) void scan_blocksums(
    int* __restrict__ block_sums, int nb, int* __restrict__ total_out) {
  __shared__ int sh[1024];
  const int tid = threadIdx.x;
  const int v = (tid < nb) ? block_sums[tid] : 0;
  sh[tid] = v;
  __syncthreads();
  int val = v;
  for (int off = 1; off < 1024; off <<= 1) {
    const int other = (tid >= off) ? sh[tid - off] : 0;
    __syncthreads();
    val += other;
    sh[tid] = val;
    __syncthreads();
  }
  if (tid < nb) block_sums[tid] = val - v;
  if (tid == 1023) *total_out = val;
}

// Writes offs (dense) and cursor (padded: one counter per 128B line).
__global__ __launch_bounds__(SCAN_BLOCK) void scan_final(
    const int* __restrict__ cnt, const int* __restrict__ block_sums,
    int* __restrict__ offs, int* __restrict__ cursor, int n) {
  __shared__ int tsum[SCAN_BLOCK];
  const int tid = threadIdx.x;
  const int base = blockIdx.x * SCAN_TILE + tid * SCAN_ITEMS;
  int local[SCAN_ITEMS];
  int s = 0;
#pragma unroll
  for (int i = 0; i < SCAN_ITEMS; ++i) {
    const int idx = base + i;
    local[i] = (idx < n) ? cnt[idx] : 0;
    s += local[i];
  }
  tsum[tid] = s;
  __syncthreads();
  int val = s;
  for (int off = 1; off < SCAN_BLOCK; off <<= 1) {
    const int other = (tid >= off) ? tsum[tid - off] : 0;
    __syncthreads();
    val += other;
    tsum[tid] = val;
    __syncthreads();
  }
  int prefix = block_sums[blockIdx.x] + (val - s);
#pragma unroll
  for (int i = 0; i < SCAN_ITEMS; ++i) {
    const int idx = base + i;
    if (idx < n) {
      offs[idx] = prefix;
      cursor[(size_t)idx * CURS] = prefix;
      prefix += local[i];
    }
  }
}

// K-batched scatter; cursor padded to kill per-cacheline atomic convoys.
__global__ __launch_bounds__(256) void scatter_kernel(
    const int* __restrict__ src, const int* __restrict__ dst,
    int* __restrict__ cursor, int* __restrict__ dst_sorted, int E) {
  const int base = blockIdx.x * (256 * SC_K) + threadIdx.x;
  int vs[SC_K], vd[SC_K], pos[SC_K];
  bool valid[SC_K];
#pragma unroll
  for (int i = 0; i < SC_K; ++i) {
    const int e = base + i * 256;
    valid[i] = (e < E);
    const int ee = valid[i] ? e : 0;
    vs[i] = src[ee];
    vd[i] = dst[ee];
  }
#pragma unroll
  for (int i = 0; i < SC_K; ++i)
    if (valid[i]) pos[i] = atomicAdd(&cursor[(size_t)vs[i] * CURS], 1);
#pragma unroll
  for (int i = 0; i < SC_K; ++i)
    if (valid[i]) dst_sorted[pos[i]] = vd[i];
}

// ---------------------------------------------------------------------------
// Aggregate: one wave per node; each HALF-wave (32 lanes x uint = 128B)
// gathers one neighbor row; 8 edges per inner iteration -> 4 independent
// loads in flight per wave. Halves merged by shfl_xor(32) at the end.
// ---------------------------------------------------------------------------
__global__ __launch_bounds__(256) void aggregate_kernel(
    const int* __restrict__ offs, const int* __restrict__ dst_sorted,
    const uint* __restrict__ hbp, const float* __restrict__ s,
    const float* __restrict__ t, float* __restrict__ out, int n_nodes) {
  const int lane = threadIdx.x & 63;
  const int ch2 = lane & 31;   // channel-pair index
  const int half = lane >> 5;  // which half-wave
  const int gwave = (blockIdx.x * blockDim.x + threadIdx.x) >> 6;
  const int waves_total = (gridDim.x * blockDim.x) >> 6;

  for (int u = gwave; u < n_nodes; u += waves_total) {
    const float su = s[u];
    const int beg = offs[u];
    const int end = offs[u + 1];

    float acc0 = 0.f, acc1 = 0.f, denom = 0.f;
    if (half == 0) {  // self-loop counted once (half 0 only)
      const float z0 = su + t[u];
      const float w0 = expf(z0 > 0.f ? z0 : ALPHA * z0);
      const uint p = hbp[(size_t)u * 32 + ch2];
      acc0 = w0 * b2f((ushort)(p & 0xffffu));
      acc1 = w0 * b2f((ushort)(p >> 16));
      denom = w0;
    }

    for (int b = beg; b < end; b += 64) {
      const int cnt = min(64, end - b);
      const int j = b + lane;
      const int idx = j < end ? j : end - 1;
      const int v = dst_sorted[idx];
      const float tv = t[v];
      const float z = su + tv;
      const float w = expf(z > 0.f ? z : ALPHA * z);

      for (int jj = 0; jj < cnt; jj += 8) {
        int vj[4];
        float wj[4];
#pragma unroll
        for (int q = 0; q < 4; ++q) {
          const int mj = jj + 2 * q + half;
          const int sl = mj < cnt ? mj : cnt - 1;
          vj[q] = __shfl(v, sl, 64);
          const float ww = __shfl(w, sl, 64);
          wj[q] = mj < cnt ? ww : 0.f;
        }
        uint p[4];
#pragma unroll
        for (int q = 0; q < 4; ++q) p[q] = hbp[(size_t)vj[q] * 32 + ch2];
#pragma unroll
        for (int q = 0; q < 4; ++q) {
          acc0 += wj[q] * b2f((ushort)(p[q] & 0xffffu));
          acc1 += wj[q] * b2f((ushort)(p[q] >> 16));
          denom += wj[q];
        }
      }
    }
    acc0 += __shfl_xor(acc0, 32, 64);
    acc1 += __shfl_xor(acc1, 32, 64);
    denom += __shfl_xor(denom, 32, 64);
    if (half == 0) {
      float2 o;
      o.x = acc0 / denom;
      o.y = acc1 / denom;
      *(float2*)&out[(size_t)u * OUT_C + ch2 * 2] = o;
    }
  }
}

extern "C" void kernel_launch(void* const* d_in, const int* in_sizes, int n_in,
                              void* d_out, int out_size, void* d_ws,
                              size_t ws_size, hipStream_t stream) {
  const float* x = (const float*)d_in[0];
  const float* W = (const float*)d_in[1];
  const float* a = (const float*)d_in[2];
  const int* edge_index = (const int*)d_in[3];

  const int n_nodes = in_sizes[0] / IN_C;
  const int E = in_sizes[3] / 2;
  const int* src = edge_index;
  const int* dst = edge_index + E;

  float* out = (float*)d_out;

  const int n_scan_blocks = (n_nodes + SCAN_TILE - 1) / SCAN_TILE;

  ushort* hb = (ushort*)d_ws;                        // n_nodes*64 bf16 (12.8MB)
  float* s = (float*)(hb + (size_t)n_nodes * OUT_C); // n_nodes
  float* t = s + n_nodes;                            // n_nodes
  int* cnt = (int*)(t + n_nodes);                    // n_nodes
  int* offs = cnt + n_nodes;                         // n_nodes+1
  int* cursor = offs + n_nodes + 1;                  // n_nodes*CURS (12.8MB)
  int* block_sums = cursor + (size_t)n_nodes * CURS; // <=1024
  int* dst_sorted = block_sums + 1024;               // E (6.4MB)

  hipMemsetAsync(cnt, 0, (size_t)n_nodes * sizeof(int), stream);

  {
    const int n_tiles = (n_nodes + 63) / 64;
    gemm_st_kernel<<<n_tiles, 256, 0, stream>>>(x, W, a, hb, s, t, n_nodes,
                                                n_tiles);
  }

  const int ebatch_grid = (E + 256 * SC_K - 1) / (256 * SC_K);
  hist_kernel<<<ebatch_grid, 256, 0, stream>>>(src, cnt, E);
  scan_partial<<<n_scan_blocks, SCAN_BLOCK, 0, stream>>>(cnt, block_sums,
                                                         n_nodes);
  scan_blocksums<<<1, 1024, 0, stream>>>(block_sums, n_scan_blocks,
                                         offs + n_nodes);
  scan_final<<<n_scan_blocks, SCAN_BLOCK, 0, stream>>>(cnt, block_sums, offs,
                                                       cursor, n_nodes);
  scatter_kernel<<<ebatch_grid, 256, 0, stream>>>(src, dst, cursor, dst_sorted,
                                                  E);

  {
    const int waves_per_block = 4;
    const int grid = (n_nodes + waves_per_block - 1) / waves_per_block;
    aggregate_kernel<<<grid, 256, 0, stream>>>(offs, dst_sorted, (const uint*)hb,
                                               s, t, out, n_nodes);
  }
}

// Round 8
// 233.854 us; speedup vs baseline: 1.4423x; 1.4423x over previous
//
#include <hip/hip_runtime.h>
#include <math.h>

#define IN_C 128
#define OUT_C 64
#define ALPHA 0.2f

#define SCAN_BLOCK 256
#define SCAN_ITEMS 4
#define SCAN_TILE (SCAN_BLOCK * SCAN_ITEMS)  // 1024 elements per block

#define LDK 136  // padded halfwords per LDS row

#define PA_EPT 16               // edges per thread in pass A
#define PA_TILE (256 * PA_EPT)  // 4096 edges per block
#define BSH 9                   // bucket shift: 512 nodes per bucket
#define NPB 512                 // nodes per bucket
#define MAXB 256                // max buckets (n <= 131072)

typedef __attribute__((ext_vector_type(8))) short short8;
typedef __attribute__((ext_vector_type(4))) float v4f;

__device__ __forceinline__ ushort f2b(float f) {  // fp32 -> bf16 RNE
  unsigned u = __float_as_uint(f);
  u += 0x7fffu + ((u >> 16) & 1u);
  return (ushort)(u >> 16);
}
__device__ __forceinline__ float b2f(ushort h) {
  return __uint_as_float(((unsigned)h) << 16);
}

// ---------------------------------------------------------------------------
// Kernel 1: h = bf16(x) @ bf16(W) via MFMA 16x16x32, fp32 accumulate.
// ---------------------------------------------------------------------------
__global__ __launch_bounds__(256) void gemm_st_kernel(
    const float* __restrict__ x, const float* __restrict__ W,
    const float* __restrict__ a, ushort* __restrict__ hb,
    float* __restrict__ s, float* __restrict__ t, int n_nodes, int n_tiles) {
  __shared__ ushort xs[64 * LDK];
  __shared__ ushort ws[64 * LDK];

  const int tid = threadIdx.x;
  const int wave = tid >> 6;
  const int lane = tid & 63;
  const int li = lane & 15;
  const int quad = lane >> 4;

  for (int i = tid; i < IN_C * OUT_C; i += 256) {
    const int k = i >> 6;
    const int n = i & 63;
    ws[n * LDK + k] = f2b(W[i]);
  }
  __syncthreads();

  short8 bfrag[4][4];
#pragma unroll
  for (int ct = 0; ct < 4; ++ct)
#pragma unroll
    for (int kk = 0; kk < 4; ++kk)
      bfrag[ct][kk] =
          *(const short8*)&ws[(ct * 16 + li) * LDK + kk * 32 + quad * 8];

  float a1v[4], a2v[4];
#pragma unroll
  for (int ct = 0; ct < 4; ++ct) {
    a1v[ct] = a[ct * 16 + li];
    a2v[ct] = a[OUT_C + ct * 16 + li];
  }

  for (int tile = blockIdx.x; tile < n_tiles; tile += gridDim.x) {
    const int row0 = tile * 64;

    __syncthreads();
    for (int i = tid; i < 64 * (IN_C / 4); i += 256) {
      const int r = i >> 5;
      const int c4 = i & 31;
      int row = row0 + r;
      row = row < n_nodes ? row : n_nodes - 1;
      const float4 v = *(const float4*)&x[(size_t)row * IN_C + c4 * 4];
      uint2 p;
      p.x = (unsigned)f2b(v.x) | ((unsigned)f2b(v.y) << 16);
      p.y = (unsigned)f2b(v.z) | ((unsigned)f2b(v.w) << 16);
      *(uint2*)&xs[r * LDK + c4 * 4] = p;
    }
    __syncthreads();

    v4f acc[4];
#pragma unroll
    for (int ct = 0; ct < 4; ++ct) acc[ct] = (v4f){0.f, 0.f, 0.f, 0.f};

    const int rbase = wave * 16;
#pragma unroll
    for (int kk = 0; kk < 4; ++kk) {
      const short8 af =
          *(const short8*)&xs[(rbase + li) * LDK + kk * 32 + quad * 8];
#pragma unroll
      for (int ct = 0; ct < 4; ++ct)
        acc[ct] = __builtin_amdgcn_mfma_f32_16x16x32_bf16(af, bfrag[ct][kk],
                                                          acc[ct], 0, 0, 0);
    }

    const int growbase = row0 + rbase + quad * 4;
    float ps[4] = {0.f, 0.f, 0.f, 0.f};
    float pt[4] = {0.f, 0.f, 0.f, 0.f};
#pragma unroll
    for (int ct = 0; ct < 4; ++ct) {
#pragma unroll
      for (int r = 0; r < 4; ++r) {
        const float hv = acc[ct][r];
        ps[r] += hv * a1v[ct];
        pt[r] += hv * a2v[ct];
        const int grow = growbase + r;
        if (grow < n_nodes)
          hb[(size_t)grow * OUT_C + ct * 16 + li] = f2b(hv);
      }
    }
#pragma unroll
    for (int m = 1; m <= 8; m <<= 1) {
#pragma unroll
      for (int r = 0; r < 4; ++r) {
        ps[r] += __shfl_xor(ps[r], m, 64);
        pt[r] += __shfl_xor(pt[r], m, 64);
      }
    }
    if (li < 4) {
      const int grow = growbase + li;
      if (grow < n_nodes) {
        const float sv = li == 0 ? ps[0] : li == 1 ? ps[1] : li == 2 ? ps[2] : ps[3];
        const float tv = li == 0 ? pt[0] : li == 1 ? pt[1] : li == 2 ? pt[2] : pt[3];
        s[grow] = sv;
        t[grow] = tv;
      }
    }
  }
}

// ---------------------------------------------------------------------------
// Pass A1: per-(block,bucket) counts via LDS histogram. NO global atomics.
// counts_tbl layout: [bucket][block] (bucket-major) for direct scanning.
// ---------------------------------------------------------------------------
__global__ __launch_bounds__(256) void pa_count(const int* __restrict__ src,
                                                int* __restrict__ counts_tbl,
                                                int nblk_a, int E) {
  __shared__ int hist[MAXB];
  const int tid = threadIdx.x;
  hist[tid] = 0;
  __syncthreads();
  const int base = blockIdx.x * PA_TILE + tid;
#pragma unroll
  for (int i = 0; i < PA_EPT; ++i) {
    const int e = base + i * 256;
    if (e < E) atomicAdd(&hist[src[e] >> BSH], 1);
  }
  __syncthreads();
  counts_tbl[(size_t)tid * nblk_a + blockIdx.x] = hist[tid];
}

// ---------------------------------------------------------------------------
// 3-pass device-wide exclusive scan (over the counts table).
// ---------------------------------------------------------------------------
__global__ __launch_bounds__(SCAN_BLOCK) void scan_partial(
    const int* __restrict__ cnt, int* __restrict__ block_sums, int n) {
  const int tid = threadIdx.x;
  const int base = blockIdx.x * SCAN_TILE + tid * SCAN_ITEMS;
  int s = 0;
#pragma unroll
  for (int i = 0; i < SCAN_ITEMS; ++i) {
    const int idx = base + i;
    if (idx < n) s += cnt[idx];
  }
  __shared__ int wsum[SCAN_BLOCK / 64];
#pragma unroll
  for (int off = 32; off; off >>= 1) s += __shfl_down(s, off, 64);
  if ((tid & 63) == 0) wsum[tid >> 6] = s;
  __syncthreads();
  if (tid == 0) {
    int tot = 0;
#pragma unroll
    for (int w = 0; w < SCAN_BLOCK / 64; ++w) tot += wsum[w];
    block_sums[blockIdx.x] = tot;
  }
}

__global__ __launch_bounds__(1024) void scan_blocksums(
    int* __restrict__ block_sums, int nb) {
  __shared__ int sh[1024];
  const int tid = threadIdx.x;
  const int v = (tid < nb) ? block_sums[tid] : 0;
  sh[tid] = v;
  __syncthreads();
  int val = v;
  for (int off = 1; off < 1024; off <<= 1) {
    const int other = (tid >= off) ? sh[tid - off] : 0;
    __syncthreads();
    val += other;
    sh[tid] = val;
    __syncthreads();
  }
  if (tid < nb) block_sums[tid] = val - v;
}

__global__ __launch_bounds__(SCAN_BLOCK) void scan_final_plain(
    const int* __restrict__ cnt, const int* __restrict__ block_sums,
    int* __restrict__ outv, int n) {
  __shared__ int tsum[SCAN_BLOCK];
  const int tid = threadIdx.x;
  const int base = blockIdx.x * SCAN_TILE + tid * SCAN_ITEMS;
  int local[SCAN_ITEMS];
  int s = 0;
#pragma unroll
  for (int i = 0; i < SCAN_ITEMS; ++i) {
    const int idx = base + i;
    local[i] = (idx < n) ? cnt[idx] : 0;
    s += local[i];
  }
  tsum[tid] = s;
  __syncthreads();
  int val = s;
  for (int off = 1; off < SCAN_BLOCK; off <<= 1) {
    const int other = (tid >= off) ? tsum[tid - off] : 0;
    __syncthreads();
    val += other;
    tsum[tid] = val;
    __syncthreads();
  }
  int prefix = block_sums[blockIdx.x] + (val - s);
#pragma unroll
  for (int i = 0; i < SCAN_ITEMS; ++i) {
    const int idx = base + i;
    if (idx < n) {
      outv[idx] = prefix;
      prefix += local[i];
    }
  }
}

// ---------------------------------------------------------------------------
// Pass A2: scatter edges into bucket regions. Positions from the scanned
// table (deterministic); within-block ranks via fast LDS atomics.
// ---------------------------------------------------------------------------
__global__ __launch_bounds__(256) void pa_scatter(
    const int* __restrict__ src, const int* __restrict__ dst,
    const int* __restrict__ bases_tbl, int* __restrict__ bsrc,
    int* __restrict__ bdst, int nblk_a, int nbuck, int E) {
  __shared__ int cur[MAXB];
  const int tid = threadIdx.x;
  cur[tid] = (tid < nbuck) ? bases_tbl[(size_t)tid * nblk_a + blockIdx.x] : 0;
  __syncthreads();
  const int base = blockIdx.x * PA_TILE + tid;
#pragma unroll
  for (int i = 0; i < PA_EPT; ++i) {
    const int e = base + i * 256;
    if (e < E) {
      const int sv = src[e];
      const int dv = dst[e];
      const int pos = atomicAdd(&cur[sv >> BSH], 1);
      bsrc[pos] = sv;
      bdst[pos] = dv;
    }
  }
}

// ---------------------------------------------------------------------------
// Pass B: one block per bucket (<=512 nodes). LDS histogram -> LDS scan ->
// write offs directly; LDS cursors place dst_sorted. All writes land in a
// ~33KB window per block -> L2 write-combining. NO global atomics.
// ---------------------------------------------------------------------------
__global__ __launch_bounds__(256) void pb_build(
    const int* __restrict__ bsrc, const int* __restrict__ bdst,
    const int* __restrict__ bases_tbl, int* __restrict__ offs,
    int* __restrict__ dst_sorted, int n_nodes, int nblk_a, int nbuck, int E) {
  __shared__ int cnt[NPB];
  __shared__ int loffs[NPB];
  __shared__ int tsum[256];
  const int b = blockIdx.x;
  const int tid = threadIdx.x;
  const int bstart = bases_tbl[(size_t)b * nblk_a];
  const int bend = (b + 1 < nbuck) ? bases_tbl[(size_t)(b + 1) * nblk_a] : E;
  const int nbase = b << BSH;

  for (int i = tid; i < NPB; i += 256) cnt[i] = 0;
  __syncthreads();
  for (int e = bstart + tid; e < bend; e += 256)
    atomicAdd(&cnt[bsrc[e] - nbase], 1);
  __syncthreads();

  // exclusive scan of cnt[512] with 256 threads (2 elements each)
  const int a0 = cnt[2 * tid];
  const int a1 = cnt[2 * tid + 1];
  const int tv = a0 + a1;
  tsum[tid] = tv;
  __syncthreads();
  int val = tv;
  for (int off = 1; off < 256; off <<= 1) {
    const int other = (tid >= off) ? tsum[tid - off] : 0;
    __syncthreads();
    val += other;
    tsum[tid] = val;
    __syncthreads();
  }
  const int pfx = val - tv;
  loffs[2 * tid] = pfx;
  loffs[2 * tid + 1] = pfx + a0;
  __syncthreads();

  // write global offs; re-init cnt as global-position cursors
  for (int i = tid; i < NPB; i += 256) {
    const int node = nbase + i;
    const int gpos = bstart + loffs[i];
    if (node < n_nodes) offs[node] = gpos;
    cnt[i] = gpos;
  }
  if (b == 0 && tid == 0) offs[n_nodes] = E;
  __syncthreads();

  for (int e = bstart + tid; e < bend; e += 256) {
    const int u = bsrc[e] - nbase;
    const int pos = atomicAdd(&cnt[u], 1);
    dst_sorted[pos] = bdst[e];
  }
}

// ---------------------------------------------------------------------------
// Aggregate: one wave per node; each HALF-wave (32 lanes x uint = 128B)
// gathers one neighbor row; 8 edges per inner iteration -> 4 independent
// loads in flight per wave. Halves merged by shfl_xor(32) at the end.
// ---------------------------------------------------------------------------
__global__ __launch_bounds__(256) void aggregate_kernel(
    const int* __restrict__ offs, const int* __restrict__ dst_sorted,
    const uint* __restrict__ hbp, const float* __restrict__ s,
    const float* __restrict__ t, float* __restrict__ out, int n_nodes) {
  const int lane = threadIdx.x & 63;
  const int ch2 = lane & 31;   // channel-pair index
  const int half = lane >> 5;  // which half-wave
  const int gwave = (blockIdx.x * blockDim.x + threadIdx.x) >> 6;
  const int waves_total = (gridDim.x * blockDim.x) >> 6;

  for (int u = gwave; u < n_nodes; u += waves_total) {
    const float su = s[u];
    const int beg = offs[u];
    const int end = offs[u + 1];

    float acc0 = 0.f, acc1 = 0.f, denom = 0.f;
    if (half == 0) {  // self-loop counted once (half 0 only)
      const float z0 = su + t[u];
      const float w0 = expf(z0 > 0.f ? z0 : ALPHA * z0);
      const uint p = hbp[(size_t)u * 32 + ch2];
      acc0 = w0 * b2f((ushort)(p & 0xffffu));
      acc1 = w0 * b2f((ushort)(p >> 16));
      denom = w0;
    }

    for (int b = beg; b < end; b += 64) {
      const int cnt = min(64, end - b);
      const int j = b + lane;
      const int idx = j < end ? j : end - 1;
      const int v = dst_sorted[idx];
      const float tv = t[v];
      const float z = su + tv;
      const float w = expf(z > 0.f ? z : ALPHA * z);

      for (int jj = 0; jj < cnt; jj += 8) {
        int vj[4];
        float wj[4];
#pragma unroll
        for (int q = 0; q < 4; ++q) {
          const int mj = jj + 2 * q + half;
          const int sl = mj < cnt ? mj : cnt - 1;
          vj[q] = __shfl(v, sl, 64);
          const float ww = __shfl(w, sl, 64);
          wj[q] = mj < cnt ? ww : 0.f;
        }
        uint p[4];
#pragma unroll
        for (int q = 0; q < 4; ++q) p[q] = hbp[(size_t)vj[q] * 32 + ch2];
#pragma unroll
        for (int q = 0; q < 4; ++q) {
          acc0 += wj[q] * b2f((ushort)(p[q] & 0xffffu));
          acc1 += wj[q] * b2f((ushort)(p[q] >> 16));
          denom += wj[q];
        }
      }
    }
    acc0 += __shfl_xor(acc0, 32, 64);
    acc1 += __shfl_xor(acc1, 32, 64);
    denom += __shfl_xor(denom, 32, 64);
    if (half == 0) {
      float2 o;
      o.x = acc0 / denom;
      o.y = acc1 / denom;
      *(float2*)&out[(size_t)u * OUT_C + ch2 * 2] = o;
    }
  }
}

extern "C" void kernel_launch(void* const* d_in, const int* in_sizes, int n_in,
                              void* d_out, int out_size, void* d_ws,
                              size_t ws_size, hipStream_t stream) {
  const float* x = (const float*)d_in[0];
  const float* W = (const float*)d_in[1];
  const float* a = (const float*)d_in[2];
  const int* edge_index = (const int*)d_in[3];

  const int n_nodes = in_sizes[0] / IN_C;
  const int E = in_sizes[3] / 2;
  const int* src = edge_index;
  const int* dst = edge_index + E;

  float* out = (float*)d_out;

  const int nbuck = (n_nodes + NPB - 1) >> BSH;           // 196
  const int nblk_a = (E + PA_TILE - 1) / PA_TILE;         // 391
  const int tbl_n = nbuck * nblk_a;                       // 76,636
  const int n_scan_blocks = (tbl_n + SCAN_TILE - 1) / SCAN_TILE;  // 75

  // Workspace layout (all 4B-aligned):
  ushort* hb = (ushort*)d_ws;                         // n*64 bf16 (12.8MB)
  float* s = (float*)(hb + (size_t)n_nodes * OUT_C);  // n
  float* t = s + n_nodes;                             // n
  int* offs = (int*)(t + n_nodes);                    // n+1
  int* counts_tbl = offs + n_nodes + 1;               // MAXB*nblk_a
  int* bases_tbl = counts_tbl + (size_t)MAXB * nblk_a;// MAXB*nblk_a
  int* block_sums = bases_tbl + (size_t)MAXB * nblk_a;// <=1024
  int* bsrc = block_sums + 1024;                      // E (6.4MB)
  int* bdst = bsrc + E;                               // E (6.4MB)
  int* dst_sorted = bdst + E;                         // E (6.4MB)

  // h (bf16), s, t via MFMA
  {
    const int n_tiles = (n_nodes + 63) / 64;
    gemm_st_kernel<<<n_tiles, 256, 0, stream>>>(x, W, a, hb, s, t, n_nodes,
                                                n_tiles);
  }

  // Atomic-free CSR build
  pa_count<<<nblk_a, 256, 0, stream>>>(src, counts_tbl, nblk_a, E);
  scan_partial<<<n_scan_blocks, SCAN_BLOCK, 0, stream>>>(counts_tbl,
                                                         block_sums, tbl_n);
  scan_blocksums<<<1, 1024, 0, stream>>>(block_sums, n_scan_blocks);
  scan_final_plain<<<n_scan_blocks, SCAN_BLOCK, 0, stream>>>(
      counts_tbl, block_sums, bases_tbl, tbl_n);
  pa_scatter<<<nblk_a, 256, 0, stream>>>(src, dst, bases_tbl, bsrc, bdst,
                                         nblk_a, nbuck, E);
  pb_build<<<nbuck, 256, 0, stream>>>(bsrc, bdst, bases_tbl, offs, dst_sorted,
                                      n_nodes, nblk_a, nbuck, E);

  // Gather-aggregate + normalize
  {
    const int waves_per_block = 4;
    const int grid = (n_nodes + waves_per_block - 1) / waves_per_block;
    aggregate_kernel<<<grid, 256, 0, stream>>>(offs, dst_sorted, (const uint*)hb,
                                               s, t, out, n_nodes);
  }
}

// Round 9
// 193.620 us; speedup vs baseline: 1.7420x; 1.2078x over previous
//
#include <hip/hip_runtime.h>
#include <math.h>

#define IN_C 128
#define OUT_C 64
#define ALPHA 0.2f

#define SCAN_BLOCK 256
#define SCAN_ITEMS 4
#define SCAN_TILE (SCAN_BLOCK * SCAN_ITEMS)  // 1024 elements per block

#define LDK 136  // padded halfwords per LDS row

#define PA_EPT 16               // edges per thread in pass A
#define PA_TILE (256 * PA_EPT)  // 4096 edges per block
#define BSH 9                   // bucket shift: 512 nodes per bucket
#define NPB 512                 // nodes per bucket
#define MAXB 256                // max buckets (n <= 131072)

typedef __attribute__((ext_vector_type(8))) short short8;
typedef __attribute__((ext_vector_type(4))) float v4f;

__device__ __forceinline__ ushort f2b(float f) {  // fp32 -> bf16 RNE
  unsigned u = __float_as_uint(f);
  u += 0x7fffu + ((u >> 16) & 1u);
  return (ushort)(u >> 16);
}
__device__ __forceinline__ float b2f(ushort h) {
  return __uint_as_float(((unsigned)h) << 16);
}

// ---------------------------------------------------------------------------
// Kernel 1: h = bf16(x) @ bf16(W) via MFMA 16x16x32, fp32 accumulate.
// ---------------------------------------------------------------------------
__global__ __launch_bounds__(256) void gemm_st_kernel(
    const float* __restrict__ x, const float* __restrict__ W,
    const float* __restrict__ a, ushort* __restrict__ hb,
    float* __restrict__ s, float* __restrict__ t, int n_nodes, int n_tiles) {
  __shared__ ushort xs[64 * LDK];
  __shared__ ushort ws[64 * LDK];

  const int tid = threadIdx.x;
  const int wave = tid >> 6;
  const int lane = tid & 63;
  const int li = lane & 15;
  const int quad = lane >> 4;

  for (int i = tid; i < IN_C * OUT_C; i += 256) {
    const int k = i >> 6;
    const int n = i & 63;
    ws[n * LDK + k] = f2b(W[i]);
  }
  __syncthreads();

  short8 bfrag[4][4];
#pragma unroll
  for (int ct = 0; ct < 4; ++ct)
#pragma unroll
    for (int kk = 0; kk < 4; ++kk)
      bfrag[ct][kk] =
          *(const short8*)&ws[(ct * 16 + li) * LDK + kk * 32 + quad * 8];

  float a1v[4], a2v[4];
#pragma unroll
  for (int ct = 0; ct < 4; ++ct) {
    a1v[ct] = a[ct * 16 + li];
    a2v[ct] = a[OUT_C + ct * 16 + li];
  }

  for (int tile = blockIdx.x; tile < n_tiles; tile += gridDim.x) {
    const int row0 = tile * 64;

    __syncthreads();
    for (int i = tid; i < 64 * (IN_C / 4); i += 256) {
      const int r = i >> 5;
      const int c4 = i & 31;
      int row = row0 + r;
      row = row < n_nodes ? row : n_nodes - 1;
      const float4 v = *(const float4*)&x[(size_t)row * IN_C + c4 * 4];
      uint2 p;
      p.x = (unsigned)f2b(v.x) | ((unsigned)f2b(v.y) << 16);
      p.y = (unsigned)f2b(v.z) | ((unsigned)f2b(v.w) << 16);
      *(uint2*)&xs[r * LDK + c4 * 4] = p;
    }
    __syncthreads();

    v4f acc[4];
#pragma unroll
    for (int ct = 0; ct < 4; ++ct) acc[ct] = (v4f){0.f, 0.f, 0.f, 0.f};

    const int rbase = wave * 16;
#pragma unroll
    for (int kk = 0; kk < 4; ++kk) {
      const short8 af =
          *(const short8*)&xs[(rbase + li) * LDK + kk * 32 + quad * 8];
#pragma unroll
      for (int ct = 0; ct < 4; ++ct)
        acc[ct] = __builtin_amdgcn_mfma_f32_16x16x32_bf16(af, bfrag[ct][kk],
                                                          acc[ct], 0, 0, 0);
    }

    const int growbase = row0 + rbase + quad * 4;
    float ps[4] = {0.f, 0.f, 0.f, 0.f};
    float pt[4] = {0.f, 0.f, 0.f, 0.f};
#pragma unroll
    for (int ct = 0; ct < 4; ++ct) {
#pragma unroll
      for (int r = 0; r < 4; ++r) {
        const float hv = acc[ct][r];
        ps[r] += hv * a1v[ct];
        pt[r] += hv * a2v[ct];
        const int grow = growbase + r;
        if (grow < n_nodes)
          hb[(size_t)grow * OUT_C + ct * 16 + li] = f2b(hv);
      }
    }
#pragma unroll
    for (int m = 1; m <= 8; m <<= 1) {
#pragma unroll
      for (int r = 0; r < 4; ++r) {
        ps[r] += __shfl_xor(ps[r], m, 64);
        pt[r] += __shfl_xor(pt[r], m, 64);
      }
    }
    if (li < 4) {
      const int grow = growbase + li;
      if (grow < n_nodes) {
        const float sv = li == 0 ? ps[0] : li == 1 ? ps[1] : li == 2 ? ps[2] : ps[3];
        const float tv = li == 0 ? pt[0] : li == 1 ? pt[1] : li == 2 ? pt[2] : pt[3];
        s[grow] = sv;
        t[grow] = tv;
      }
    }
  }
}

// ---------------------------------------------------------------------------
// Pass A1: per-(block,bucket) counts via LDS histogram; int4 edge reads.
// ---------------------------------------------------------------------------
__global__ __launch_bounds__(256) void pa_count(const int* __restrict__ src,
                                                int* __restrict__ counts_tbl,
                                                int nblk_a, int E) {
  __shared__ int hist[MAXB];
  const int tid = threadIdx.x;
  hist[tid] = 0;
  __syncthreads();
  const int e0 = blockIdx.x * PA_TILE + tid * PA_EPT;
  if (e0 + PA_EPT <= E) {
#pragma unroll
    for (int i = 0; i < PA_EPT / 4; ++i) {
      const int4 v = *(const int4*)(src + e0 + i * 4);
      atomicAdd(&hist[v.x >> BSH], 1);
      atomicAdd(&hist[v.y >> BSH], 1);
      atomicAdd(&hist[v.z >> BSH], 1);
      atomicAdd(&hist[v.w >> BSH], 1);
    }
  } else {
    for (int e = e0; e < E; ++e) atomicAdd(&hist[src[e] >> BSH], 1);
  }
  __syncthreads();
  counts_tbl[(size_t)tid * nblk_a + blockIdx.x] = hist[tid];
}

// ---------------------------------------------------------------------------
// 3-pass device-wide exclusive scan (over the counts table).
// ---------------------------------------------------------------------------
__global__ __launch_bounds__(SCAN_BLOCK) void scan_partial(
    const int* __restrict__ cnt, int* __restrict__ block_sums, int n) {
  const int tid = threadIdx.x;
  const int base = blockIdx.x * SCAN_TILE + tid * SCAN_ITEMS;
  int s = 0;
#pragma unroll
  for (int i = 0; i < SCAN_ITEMS; ++i) {
    const int idx = base + i;
    if (idx < n) s += cnt[idx];
  }
  __shared__ int wsum[SCAN_BLOCK / 64];
#pragma unroll
  for (int off = 32; off; off >>= 1) s += __shfl_down(s, off, 64);
  if ((tid & 63) == 0) wsum[tid >> 6] = s;
  __syncthreads();
  if (tid == 0) {
    int tot = 0;
#pragma unroll
    for (int w = 0; w < SCAN_BLOCK / 64; ++w) tot += wsum[w];
    block_sums[blockIdx.x] = tot;
  }
}

__global__ __launch_bounds__(1024) void scan_blocksums(
    int* __restrict__ block_sums, int nb) {
  __shared__ int sh[1024];
  const int tid = threadIdx.x;
  const int v = (tid < nb) ? block_sums[tid] : 0;
  sh[tid] = v;
  __syncthreads();
  int val = v;
  for (int off = 1; off < 1024; off <<= 1) {
    const int other = (tid >= off) ? sh[tid - off] : 0;
    __syncthreads();
    val += other;
    sh[tid] = val;
    __syncthreads();
  }
  if (tid < nb) block_sums[tid] = val - v;
}

__global__ __launch_bounds__(SCAN_BLOCK) void scan_final_plain(
    const int* __restrict__ cnt, const int* __restrict__ block_sums,
    int* __restrict__ outv, int n) {
  __shared__ int tsum[SCAN_BLOCK];
  const int tid = threadIdx.x;
  const int base = blockIdx.x * SCAN_TILE + tid * SCAN_ITEMS;
  int local[SCAN_ITEMS];
  int s = 0;
#pragma unroll
  for (int i = 0; i < SCAN_ITEMS; ++i) {
    const int idx = base + i;
    local[i] = (idx < n) ? cnt[idx] : 0;
    s += local[i];
  }
  tsum[tid] = s;
  __syncthreads();
  int val = s;
  for (int off = 1; off < SCAN_BLOCK; off <<= 1) {
    const int other = (tid >= off) ? tsum[tid - off] : 0;
    __syncthreads();
    val += other;
    tsum[tid] = val;
    __syncthreads();
  }
  int prefix = block_sums[blockIdx.x] + (val - s);
#pragma unroll
  for (int i = 0; i < SCAN_ITEMS; ++i) {
    const int idx = base + i;
    if (idx < n) {
      outv[idx] = prefix;
      prefix += local[i];
    }
  }
}

// ---------------------------------------------------------------------------
// Pass A2: scatter edges into bucket regions as packed (src,dst) int2.
// ---------------------------------------------------------------------------
__global__ __launch_bounds__(256) void pa_scatter(
    const int* __restrict__ src, const int* __restrict__ dst,
    const int* __restrict__ bases_tbl, int2* __restrict__ bpair, int nblk_a,
    int nbuck, int E) {
  __shared__ int cur[MAXB];
  const int tid = threadIdx.x;
  cur[tid] = (tid < nbuck) ? bases_tbl[(size_t)tid * nblk_a + blockIdx.x] : 0;
  __syncthreads();
  const int e0 = blockIdx.x * PA_TILE + tid * PA_EPT;
  if (e0 + PA_EPT <= E) {
#pragma unroll
    for (int i = 0; i < PA_EPT / 4; ++i) {
      const int4 sv = *(const int4*)(src + e0 + i * 4);
      const int4 dv = *(const int4*)(dst + e0 + i * 4);
      const int p0 = atomicAdd(&cur[sv.x >> BSH], 1);
      const int p1 = atomicAdd(&cur[sv.y >> BSH], 1);
      const int p2 = atomicAdd(&cur[sv.z >> BSH], 1);
      const int p3 = atomicAdd(&cur[sv.w >> BSH], 1);
      bpair[p0] = make_int2(sv.x, dv.x);
      bpair[p1] = make_int2(sv.y, dv.y);
      bpair[p2] = make_int2(sv.z, dv.z);
      bpair[p3] = make_int2(sv.w, dv.w);
    }
  } else {
    for (int e = e0; e < E; ++e) {
      const int sv = src[e];
      const int dv = dst[e];
      const int p = atomicAdd(&cur[sv >> BSH], 1);
      bpair[p] = make_int2(sv, dv);
    }
  }
}

// ---------------------------------------------------------------------------
// Pass B: one block per bucket. LDS histogram -> LDS scan -> offs + place
// dst_sorted via LDS cursors. 8B packed reads.
// ---------------------------------------------------------------------------
__global__ __launch_bounds__(256) void pb_build(
    const int2* __restrict__ bpair, const int* __restrict__ bases_tbl,
    int* __restrict__ offs, int* __restrict__ dst_sorted, int n_nodes,
    int nblk_a, int nbuck, int E) {
  __shared__ int cnt[NPB];
  __shared__ int loffs[NPB];
  __shared__ int tsum[256];
  const int b = blockIdx.x;
  const int tid = threadIdx.x;
  const int bstart = bases_tbl[(size_t)b * nblk_a];
  const int bend = (b + 1 < nbuck) ? bases_tbl[(size_t)(b + 1) * nblk_a] : E;
  const int nbase = b << BSH;

  for (int i = tid; i < NPB; i += 256) cnt[i] = 0;
  __syncthreads();
  for (int e = bstart + tid; e < bend; e += 256)
    atomicAdd(&cnt[bpair[e].x - nbase], 1);
  __syncthreads();

  const int a0 = cnt[2 * tid];
  const int a1 = cnt[2 * tid + 1];
  const int tv = a0 + a1;
  tsum[tid] = tv;
  __syncthreads();
  int val = tv;
  for (int off = 1; off < 256; off <<= 1) {
    const int other = (tid >= off) ? tsum[tid - off] : 0;
    __syncthreads();
    val += other;
    tsum[tid] = val;
    __syncthreads();
  }
  const int pfx = val - tv;
  loffs[2 * tid] = pfx;
  loffs[2 * tid + 1] = pfx + a0;
  __syncthreads();

  for (int i = tid; i < NPB; i += 256) {
    const int node = nbase + i;
    const int gpos = bstart + loffs[i];
    if (node < n_nodes) offs[node] = gpos;
    cnt[i] = gpos;
  }
  if (b == 0 && tid == 0) offs[n_nodes] = E;
  __syncthreads();

  for (int e = bstart + tid; e < bend; e += 256) {
    const int2 pr = bpair[e];
    const int pos = atomicAdd(&cnt[pr.x - nbase], 1);
    dst_sorted[pos] = pr.y;
  }
}

// ---------------------------------------------------------------------------
// Aggregate: one wave per node. Stage 64 (v,w) pairs in LDS (1 ds_write_b64),
// inner loop: uniform ds_read_b64 broadcasts, zero-padded to 16 -> no clamps,
// 8 gather loads in flight per wave. Halves merged by shfl_xor(32).
// ---------------------------------------------------------------------------
__global__ __launch_bounds__(256) void aggregate_kernel(
    const int* __restrict__ offs, const int* __restrict__ dst_sorted,
    const uint* __restrict__ hbp, const float* __restrict__ s,
    const float* __restrict__ t, float* __restrict__ out, int n_nodes) {
  __shared__ int2 stage[4][64];
  const int wv = threadIdx.x >> 6;
  const int lane = threadIdx.x & 63;
  const int ch2 = lane & 31;   // channel-pair index
  const int half = lane >> 5;  // which half-wave
  const int gwave = (blockIdx.x * blockDim.x + threadIdx.x) >> 6;
  const int waves_total = (gridDim.x * blockDim.x) >> 6;

  for (int u = gwave; u < n_nodes; u += waves_total) {
    const float su = s[u];
    const int beg = offs[u];
    const int end = offs[u + 1];

    float acc0 = 0.f, acc1 = 0.f, denom = 0.f;
    if (half == 0) {  // self-loop counted once (half 0 only)
      const float z0 = su + t[u];
      const float w0 = expf(z0 > 0.f ? z0 : ALPHA * z0);
      const uint p = hbp[(size_t)u * 32 + ch2];
      acc0 = w0 * __uint_as_float(p << 16);
      acc1 = w0 * __uint_as_float(p & 0xffff0000u);
      denom = w0;
    }

    for (int b = beg; b < end; b += 64) {
      const int rem = end - b;
      // Stage: lane j computes edge b+j's (neighbor, exp-weight); w=0 pad.
      const int j = b + lane;
      const int idx = j < end ? j : end - 1;
      const int v = dst_sorted[idx];
      const float tv = t[v];
      const float z = su + tv;
      float w = expf(z > 0.f ? z : ALPHA * z);
      if (j >= end) w = 0.f;
      stage[wv][lane] = make_int2(v, __float_as_int(w));

      const int npad = min((rem + 15) & ~15, 64);
      for (int jj = 0; jj < npad; jj += 16) {
        int vj[8];
        float wj[8];
#pragma unroll
        for (int q = 0; q < 8; ++q) {
          const int2 evw = stage[wv][jj + 8 * half + q];
          vj[q] = evw.x;
          wj[q] = __int_as_float(evw.y);
        }
        uint p[8];
#pragma unroll
        for (int q = 0; q < 8; ++q) p[q] = hbp[(size_t)vj[q] * 32 + ch2];
#pragma unroll
        for (int q = 0; q < 8; ++q) {
          acc0 += wj[q] * __uint_as_float(p[q] << 16);
          acc1 += wj[q] * __uint_as_float(p[q] & 0xffff0000u);
          denom += wj[q];
        }
      }
    }
    acc0 += __shfl_xor(acc0, 32, 64);
    acc1 += __shfl_xor(acc1, 32, 64);
    denom += __shfl_xor(denom, 32, 64);
    if (half == 0) {
      float2 o;
      o.x = acc0 / denom;
      o.y = acc1 / denom;
      *(float2*)&out[(size_t)u * OUT_C + ch2 * 2] = o;
    }
  }
}

extern "C" void kernel_launch(void* const* d_in, const int* in_sizes, int n_in,
                              void* d_out, int out_size, void* d_ws,
                              size_t ws_size, hipStream_t stream) {
  const float* x = (const float*)d_in[0];
  const float* W = (const float*)d_in[1];
  const float* a = (const float*)d_in[2];
  const int* edge_index = (const int*)d_in[3];

  const int n_nodes = in_sizes[0] / IN_C;
  const int E = in_sizes[3] / 2;
  const int* src = edge_index;
  const int* dst = edge_index + E;

  float* out = (float*)d_out;

  const int nbuck = (n_nodes + NPB - 1) >> BSH;
  const int nblk_a = (E + PA_TILE - 1) / PA_TILE;
  const int tbl_n = nbuck * nblk_a;
  const int n_scan_blocks = (tbl_n + SCAN_TILE - 1) / SCAN_TILE;

  // Workspace layout (8B-aligned chunks first):
  ushort* hb = (ushort*)d_ws;                          // n*64 bf16 (12.8MB)
  int2* bpair = (int2*)(hb + (size_t)n_nodes * OUT_C); // E int2 (12.8MB)
  float* s = (float*)(bpair + E);                      // n
  float* t = s + n_nodes;                              // n
  int* offs = (int*)(t + n_nodes);                     // n+1
  int* counts_tbl = offs + n_nodes + 1;                // MAXB*nblk_a
  int* bases_tbl = counts_tbl + (size_t)MAXB * nblk_a; // MAXB*nblk_a
  int* block_sums = bases_tbl + (size_t)MAXB * nblk_a; // <=1024
  int* dst_sorted = block_sums + 1024;                 // E (6.4MB)

  // h (bf16), s, t via MFMA
  {
    const int n_tiles = (n_nodes + 63) / 64;
    gemm_st_kernel<<<n_tiles, 256, 0, stream>>>(x, W, a, hb, s, t, n_nodes,
                                                n_tiles);
  }

  // Atomic-free CSR build
  pa_count<<<nblk_a, 256, 0, stream>>>(src, counts_tbl, nblk_a, E);
  scan_partial<<<n_scan_blocks, SCAN_BLOCK, 0, stream>>>(counts_tbl,
                                                         block_sums, tbl_n);
  scan_blocksums<<<1, 1024, 0, stream>>>(block_sums, n_scan_blocks);
  scan_final_plain<<<n_scan_blocks, SCAN_BLOCK, 0, stream>>>(
      counts_tbl, block_sums, bases_tbl, tbl_n);
  pa_scatter<<<nblk_a, 256, 0, stream>>>(src, dst, bases_tbl, bpair, nblk_a,
                                         nbuck, E);
  pb_build<<<nbuck, 256, 0, stream>>>(bpair, bases_tbl, offs, dst_sorted,
                                      n_nodes, nblk_a, nbuck, E);

  // Gather-aggregate + normalize
  {
    const int waves_per_block = 4;
    const int grid = (n_nodes + waves_per_block - 1) / waves_per_block;
    aggregate_kernel<<<grid, 256, 0, stream>>>(offs, dst_sorted, (const uint*)hb,
                                               s, t, out, n_nodes);
  }
}